// Round 15
// baseline (83.530 us; speedup 1.0000x reference)
//
#include <hip/hip_runtime.h>

#define BATCH 512
#define SEQ   512
#define VOCAB 1000
#define EMB   100
#define UNITS 64
#define SC    2.88539008177792681f   // 2*log2(e): exp2(SC*s) == e^{2s}

typedef float     v2f   __attribute__((ext_vector_type(2)));
typedef unsigned  u32x2 __attribute__((ext_vector_type(2)));
typedef _Float16  h2    __attribute__((ext_vector_type(2)));

// ---------------------------------------------------------------------------
// Kernel 1: P[v][u] = SC*( (emb[v]@Wxh)[u] + b[u] + colsum(Whh)[u] )
// (r6-proven colsum fold for the r-recurrence; P stays fp32.)
// ---------------------------------------------------------------------------
__global__ __launch_bounds__(64) void proj_kernel(
    const float* __restrict__ emb, const float* __restrict__ Wxh,
    const float* __restrict__ bias, const float* __restrict__ Whh,
    float* __restrict__ P) {
  const int v = blockIdx.x;
  const int u = threadIdx.x;
  const float* e = emb + v * EMB;
  float acc = bias[u];
#pragma unroll 5
  for (int d = 0; d < EMB; ++d) acc += e[d] * Wxh[d * UNITS + u];
  float csum = 0.f;
#pragma unroll 8
  for (int i = 0; i < UNITS; ++i) csum += Whh[i * UNITS + u];
  P[v * UNITS + u] = SC * (acc + csum);
}

// ---------------------------------------------------------------------------
// DPP machinery. Pair all-gather of the lane's own 16-lane row (8 packed
// f16x2 sources at the row's even lanes). Two-level: 2 quad-perm broadcasts
// (g0,g1), then row_ror 4/8/12 -- in the scan the 6 level-2 rotations are
// FUSED into v_dot2c_f32_f16 DPP modifiers (same ctrl codes), so only the
// 2 level-1 movs remain as separate instructions. Slot->source permutation
// calibrated at runtime on lane_id with the same ctrls (GATHER8) and folded
// into the f16 weight-pair layout.
// ---------------------------------------------------------------------------
#define DPP_I(src, ctrl) __builtin_amdgcn_update_dpp(0, (src), (ctrl), 0xF, 0xF, true)

#define GATHER8(v_, g_)                                             \
  do {                                                              \
    g_[0] = DPP_I((v_), 0x00);   /* quad_perm:[0,0,0,0] */          \
    g_[1] = DPP_I((v_), 0xAA);   /* quad_perm:[2,2,2,2] */          \
    g_[2] = DPP_I(g_[0], 0x124); g_[3] = DPP_I(g_[1], 0x124);       \
    g_[4] = DPP_I(g_[0], 0x128); g_[5] = DPP_I(g_[1], 0x128);       \
    g_[6] = DPP_I(g_[0], 0x12C); g_[7] = DPP_I(g_[1], 0x12C);       \
  } while (0)

// Raw permlane swap returning BOTH outputs (r10-proven).
#if __has_builtin(__builtin_amdgcn_permlane16_swap) && \
    __has_builtin(__builtin_amdgcn_permlane32_swap)
__device__ __forceinline__ u32x2 plswap16(unsigned x, unsigned y) {
  return __builtin_amdgcn_permlane16_swap(x, y, false, false);
}
__device__ __forceinline__ u32x2 plswap32(unsigned x, unsigned y) {
  return __builtin_amdgcn_permlane32_swap(x, y, false, false);
}
#else
__device__ __forceinline__ u32x2 plswap16(unsigned x, unsigned y) {
  asm("s_nop 1\n\tv_permlane16_swap_b32 %0, %1" : "+v"(x), "+v"(y));
  u32x2 r; r.x = x; r.y = y; return r;
}
__device__ __forceinline__ u32x2 plswap32(unsigned x, unsigned y) {
  asm("s_nop 1\n\tv_permlane32_swap_b32 %0, %1" : "+v"(x), "+v"(y));
  u32x2 r; r.x = x; r.y = y; return r;
}
#endif

// Selection-free combine (r5/r10-proven algebra).
__device__ __forceinline__ float swadd16(float vd, float vs) {
  u32x2 p = plswap16((unsigned)__float_as_int(vd), (unsigned)__float_as_int(vs));
  return __int_as_float((int)p.x) + __int_as_float((int)p.y);
}
__device__ __forceinline__ float swadd32(float vd, float vs) {
  u32x2 p = plswap32((unsigned)__float_as_int(vd), (unsigned)__float_as_int(vs));
  return __int_as_float((int)p.x) + __int_as_float((int)p.y);
}

// f16 pair dot with f32 accumulate (slots 0,1: plain VOP3P form).
__device__ __forceinline__ float dot2(int a, int b, float c) {
#if __has_builtin(__builtin_amdgcn_fdot2)
  return __builtin_amdgcn_fdot2(__builtin_bit_cast(h2, a),
                                __builtin_bit_cast(h2, b), c, false);
#else
  h2 ha = __builtin_bit_cast(h2, a), hb = __builtin_bit_cast(h2, b);
  return c + (float)ha.x * (float)hb.x + (float)ha.y * (float)hb.y;
#endif
}

// ---------------------------------------------------------------------------
// Kernel 2: sequential scan on r(t) = 1/(e^{2s}+1), one row per wave.
// Slot model (r2..r14-calibrated, ~5-6.3 cyc/slot): r14 step = ~56 slots =
// 390 cyc. This round fuses the 6 level-2 gather rotations into the dot
// instructions via VOP2 v_dot2c_f32_f16 + DPP row_ror (one asm block,
// s_nop-guarded: DPP reads inside asm are invisible to the compiler's
// hazard recognizer). Per step: pack(2) + gather-L1(2) + 8 fdot2 +
// 24 dot2c-dpp + combine(6) + a-fold(1) + exp2/add/rcp(3) + P/token(~4).
// ---------------------------------------------------------------------------
__global__ __launch_bounds__(64)
__attribute__((amdgpu_waves_per_eu(1, 1)))
void scan_kernel(
    const int* __restrict__ tok, const float* __restrict__ P,
    const float* __restrict__ Whh, const float* __restrict__ Wout,
    const float* __restrict__ bout, float* __restrict__ out) {
  const int row  = blockIdx.x;
  const int lane = threadIdx.x;

  // ---- calibration: pair-gather permutation (slot s -> even source lane) --
  int g2cal[8];
  GATHER8(lane, g2cal);  // g2cal[s] = e_s (even unit index; pair = e_s, e_s+1)

  // ---- calibration: swap convention flags F16/F32 (r5/r10-proven probe) ---
  u32x2 pr16 = plswap16((unsigned)lane, (unsigned)(1000 + lane));
  const int b4  = (lane >> 4) & 1;
  const int F16 = ((((int)pr16.x >= 1000) ? 1 : 0) ^ b4) ? 0 : 1;
  u32x2 pr32 = plswap32((unsigned)lane, (unsigned)(1000 + lane));
  const int b5  = (lane >> 5) & 1;
  const int F32 = ((((int)pr32.x >= 1000) ? 1 : 0) ^ b5) ? 0 : 1;

  // ---- weights: partial (j,k) carries column (lane&15)|((j^F16)<<4)|
  // ((k^F32)<<5); pair-slots permuted to gather order; scaled by -2*SC;
  // converted RNE to f16 pairs; pinned in VGPRs (32 regs total) ----
  const int cb  = lane & 15;
  const int c00 = cb | ((0 ^ F16) << 4) | ((0 ^ F32) << 5);
  const int c01 = cb | ((0 ^ F16) << 4) | ((1 ^ F32) << 5);
  const int c10 = cb | ((1 ^ F16) << 4) | ((0 ^ F32) << 5);
  const int c11 = cb | ((1 ^ F16) << 4) | ((1 ^ F32) << 5);
  int w00[8], w01[8], w10[8], w11[8];
#pragma unroll
  for (int s = 0; s < 8; ++s) {
    const long i0 = (long)g2cal[s] * UNITS;       // unit e_s
    const long i1 = i0 + UNITS;                   // unit e_s + 1
    h2 t00, t01, t10, t11;
    t00.x = (_Float16)(-2.f * SC * Whh[i0 + c00]);
    t00.y = (_Float16)(-2.f * SC * Whh[i1 + c00]);
    t01.x = (_Float16)(-2.f * SC * Whh[i0 + c01]);
    t01.y = (_Float16)(-2.f * SC * Whh[i1 + c01]);
    t10.x = (_Float16)(-2.f * SC * Whh[i0 + c10]);
    t10.y = (_Float16)(-2.f * SC * Whh[i1 + c10]);
    t11.x = (_Float16)(-2.f * SC * Whh[i0 + c11]);
    t11.y = (_Float16)(-2.f * SC * Whh[i1 + c11]);
    int u0 = __builtin_bit_cast(int, t00), u1 = __builtin_bit_cast(int, t01);
    int u2 = __builtin_bit_cast(int, t10), u3 = __builtin_bit_cast(int, t11);
    asm volatile("" : "+v"(u0), "+v"(u1), "+v"(u2), "+v"(u3));
    w00[s] = u0; w01[s] = u1; w10[s] = u2; w11[s] = u3;
  }

  const int* trow = tok + (long)row * SEQ;

  float r = 0.5f;  // h = 0  <=>  r = 0.5

  // ---- one scan step ----
#define STEP(TOKPF)                                                           \
  do {                                                                        \
    float a_cur = a0;                                                         \
    a0 = a1;                                                                  \
    a1 = P[(long)(TOKPF) * UNITS + lane]; /* row t+2, dist-2 prefetch */      \
    /* pack (r[e], r[e+1]) into even lanes: qp[1,1,3,3] + cvt_pkrtz */        \
    int nbi = DPP_I(__float_as_int(r), 0xF5);                                 \
    int pki = __builtin_bit_cast(                                             \
        int, __builtin_amdgcn_cvt_pkrtz(r, __int_as_float(nbi)));             \
    /* gather level 1 only (level 2 fused into dot2c DPP below) */            \
    int g0 = DPP_I(pki, 0x00);                                                \
    int g1 = DPP_I(pki, 0xAA);                                                \
    /* slots 0,1: plain dots start the 4 chains */                            \
    float q00 = dot2(g1, w00[1], dot2(g0, w00[0], 0.f));                      \
    float q01 = dot2(g1, w01[1], dot2(g0, w01[0], 0.f));                      \
    float q10 = dot2(g1, w10[1], dot2(g0, w10[0], 0.f));                      \
    float q11 = dot2(g1, w11[1], dot2(g0, w11[0], 0.f));                      \
    /* slots 2..7: v_dot2c_f32_f16 with fused row_ror DPP on g0/g1.          \
       One block: s_nop guards (VALU->DPP in, asm->permlane out). */          \
    asm("s_nop 1\n\t"                                                         \
        "v_dot2c_f32_f16 %0, %4, %6  row_ror:4  row_mask:0xf bank_mask:0xf\n\t" \
        "v_dot2c_f32_f16 %1, %4, %7  row_ror:4  row_mask:0xf bank_mask:0xf\n\t" \
        "v_dot2c_f32_f16 %2, %4, %8  row_ror:4  row_mask:0xf bank_mask:0xf\n\t" \
        "v_dot2c_f32_f16 %3, %4, %9  row_ror:4  row_mask:0xf bank_mask:0xf\n\t" \
        "v_dot2c_f32_f16 %0, %5, %10 row_ror:4  row_mask:0xf bank_mask:0xf\n\t" \
        "v_dot2c_f32_f16 %1, %5, %11 row_ror:4  row_mask:0xf bank_mask:0xf\n\t" \
        "v_dot2c_f32_f16 %2, %5, %12 row_ror:4  row_mask:0xf bank_mask:0xf\n\t" \
        "v_dot2c_f32_f16 %3, %5, %13 row_ror:4  row_mask:0xf bank_mask:0xf\n\t" \
        "v_dot2c_f32_f16 %0, %4, %14 row_ror:8  row_mask:0xf bank_mask:0xf\n\t" \
        "v_dot2c_f32_f16 %1, %4, %15 row_ror:8  row_mask:0xf bank_mask:0xf\n\t" \
        "v_dot2c_f32_f16 %2, %4, %16 row_ror:8  row_mask:0xf bank_mask:0xf\n\t" \
        "v_dot2c_f32_f16 %3, %4, %17 row_ror:8  row_mask:0xf bank_mask:0xf\n\t" \
        "v_dot2c_f32_f16 %0, %5, %18 row_ror:8  row_mask:0xf bank_mask:0xf\n\t" \
        "v_dot2c_f32_f16 %1, %5, %19 row_ror:8  row_mask:0xf bank_mask:0xf\n\t" \
        "v_dot2c_f32_f16 %2, %5, %20 row_ror:8  row_mask:0xf bank_mask:0xf\n\t" \
        "v_dot2c_f32_f16 %3, %5, %21 row_ror:8  row_mask:0xf bank_mask:0xf\n\t" \
        "v_dot2c_f32_f16 %0, %4, %22 row_ror:12 row_mask:0xf bank_mask:0xf\n\t" \
        "v_dot2c_f32_f16 %1, %4, %23 row_ror:12 row_mask:0xf bank_mask:0xf\n\t" \
        "v_dot2c_f32_f16 %2, %4, %24 row_ror:12 row_mask:0xf bank_mask:0xf\n\t" \
        "v_dot2c_f32_f16 %3, %4, %25 row_ror:12 row_mask:0xf bank_mask:0xf\n\t" \
        "v_dot2c_f32_f16 %0, %5, %26 row_ror:12 row_mask:0xf bank_mask:0xf\n\t" \
        "v_dot2c_f32_f16 %1, %5, %27 row_ror:12 row_mask:0xf bank_mask:0xf\n\t" \
        "v_dot2c_f32_f16 %2, %5, %28 row_ror:12 row_mask:0xf bank_mask:0xf\n\t" \
        "v_dot2c_f32_f16 %3, %5, %29 row_ror:12 row_mask:0xf bank_mask:0xf\n\t" \
        "s_nop 1"                                                             \
        : "+v"(q00), "+v"(q01), "+v"(q10), "+v"(q11)                          \
        : "v"(g0), "v"(g1),                                                   \
          "v"(w00[2]), "v"(w01[2]), "v"(w10[2]), "v"(w11[2]),                 \
          "v"(w00[3]), "v"(w01[3]), "v"(w10[3]), "v"(w11[3]),                 \
          "v"(w00[4]), "v"(w01[4]), "v"(w10[4]), "v"(w11[4]),                 \
          "v"(w00[5]), "v"(w01[5]), "v"(w10[5]), "v"(w11[5]),                 \
          "v"(w00[6]), "v"(w01[6]), "v"(w10[6]), "v"(w11[6]),                 \
          "v"(w00[7]), "v"(w01[7]), "v"(w10[7]), "v"(w11[7]));                \
    float g0s = swadd16(q10, q00);                                            \
    float g1s = swadd16(q11, q01);                                            \
    float yv  = swadd32(g1s, g0s) + a_cur;                                    \
    r = __builtin_amdgcn_rcpf(__builtin_amdgcn_exp2f(yv) + 1.f);              \
  } while (0)

  // Token SGPR blocks, ping-pong (r12-proven): all indices compile-time.
  int tka[16], tkb[16];
#pragma unroll
  for (int i = 0; i < 16; ++i) tka[i] = trow[i];

  // P-value ring: a0 = row(t), a1 = row(t+1).
  float a0 = P[(long)tka[0] * UNITS + lane];
  float a1 = P[(long)tka[1] * UNITS + lane];

  for (int c = 0; c < SEQ / 16; c += 2) {
#pragma unroll
    for (int i = 0; i < 16; ++i) tkb[i] = trow[(c + 1) * 16 + i];
#pragma unroll
    for (int i = 0; i < 16; ++i) {
      STEP(i < 14 ? tka[i + 2] : tkb[i - 14]);
    }
    const int nb = (c + 2 < SEQ / 16) ? (c + 2) * 16 : SEQ - 1;
    const int st = (c + 2 < SEQ / 16) ? 1 : 0;
#pragma unroll
    for (int i = 0; i < 16; ++i) tka[i] = trow[nb + st * i];
#pragma unroll
    for (int i = 0; i < 16; ++i) {
      STEP(i < 14 ? tkb[i + 2] : tka[i - 14]);
    }
  }
#undef STEP

  // h = 1 - 2r (once, fp32); out[row] = sigmoid(sum_j h[j]*Wout[j] + bout)
  float h = __builtin_fmaf(-2.f, r, 1.f);
  float p = h * Wout[lane];
#pragma unroll
  for (int off = 32; off > 0; off >>= 1) p += __shfl_xor(p, off);
  if (lane == 0) out[row] = 1.f / (1.f + __expf(-(p + bout[0])));
}

extern "C" void kernel_launch(void* const* d_in, const int* in_sizes, int n_in,
                              void* d_out, int out_size, void* d_ws, size_t ws_size,
                              hipStream_t stream) {
  const int*   tok  = (const int*)  d_in[0];  // [BATCH, SEQ] int32
  const float* emb  = (const float*)d_in[1];  // [VOCAB, EMB]
  const float* Wxh  = (const float*)d_in[2];  // [EMB, UNITS]
  const float* Whh  = (const float*)d_in[3];  // [UNITS, UNITS]
  const float* bias = (const float*)d_in[4];  // [UNITS]
  const float* Wout = (const float*)d_in[5];  // [UNITS, 1]
  const float* bout = (const float*)d_in[6];  // [1]
  float* out = (float*)d_out;                 // [BATCH, 1] fp32

  float* P = (float*)d_ws;                    // VOCAB*UNITS fp32 = 256 KB

  proj_kernel<<<VOCAB, 64, 0, stream>>>(emb, Wxh, bias, Whh, P);
  scan_kernel<<<BATCH, 64, 0, stream>>>(tok, P, Whh, Wout, bout, out);
}